// Round 15
// baseline (99.751 us; speedup 1.0000x reference)
//
#include <hip/hip_runtime.h>
#include <hip/hip_bf16.h>
#include <math.h>

#define B_ 2
#define S_ 2048
#define D_ 1024
#define H_ 16
#define G_ 4
#define HD_ 64

typedef float f32x4  __attribute__((ext_vector_type(4)));
typedef float f32x16 __attribute__((ext_vector_type(16)));
typedef short s16x8  __attribute__((ext_vector_type(8)));
typedef unsigned short u16x4 __attribute__((ext_vector_type(4)));
typedef unsigned int   u32x4 __attribute__((ext_vector_type(4)));

__device__ __forceinline__ unsigned short f2b(float f) {
    __hip_bfloat16 h = __float2bfloat16(f);
    return __builtin_bit_cast(unsigned short, h);
}
__device__ __forceinline__ unsigned cvtpk(float lo, float hi) {
    unsigned r;
    asm("v_cvt_pk_bf16_f32 %0, %1, %2" : "=v"(r) : "v"(lo), "v"(hi));
    return r;
}
__device__ __forceinline__ void plswap(unsigned &a, unsigned &b) {
    asm("v_permlane32_swap_b32 %0, %1" : "+v"(a), "+v"(b));
}
__device__ __forceinline__ s16x8 pack8(const float* v) {
    unsigned a0 = cvtpk(v[0], v[1]);
    unsigned a1 = cvtpk(v[2], v[3]);
    unsigned a2 = cvtpk(v[4], v[5]);
    unsigned a3 = cvtpk(v[6], v[7]);
    plswap(a0, a2); plswap(a1, a3);
    u32x4 aw = {a0, a1, a2, a3};
    return __builtin_bit_cast(s16x8, aw);
}

#define MFMA16(a, b, c) __builtin_amdgcn_mfma_f32_16x16x32_bf16(a, b, c, 0, 0, 0)
#define MFMA32(a, b, c) __builtin_amdgcn_mfma_f32_32x32x16_bf16(a, b, c, 0, 0, 0)

#define GLOAD16(gp, lp) __builtin_amdgcn_global_load_lds(                      \
    (const __attribute__((address_space(1))) void*)(gp),                      \
    (__attribute__((address_space(3))) void*)(lp), 16, 0, 0)

// ---------------- prep: bf16 casts + pooled K/V weights + rope tables -------
__global__ __launch_bounds__(256)
void prep_all(const float* __restrict__ x,  const float* __restrict__ Wq,
              const float* __restrict__ Wk, const float* __restrict__ Wv,
              const float* __restrict__ Wo,
              unsigned short* __restrict__ xb, unsigned short* __restrict__ wb,
              unsigned short* __restrict__ wob,
              float* __restrict__ cost, float* __restrict__ sint)
{
    const int NQ_WB = (1536*1024)/4;
    const int NQ_WO = (1024*1024)/4;
    const int NQ_X  = (B_*S_*D_)/4;
    int q = blockIdx.x*256 + threadIdx.x;
    if (q < NQ_WB) {
        const int idx = q*4, row = idx >> 10, c = idx & 1023;
        u16x4 o;
        if (row < 1024) {
            f32x4 v = *(const f32x4*)&Wq[(size_t)row*1024 + c];
            #pragma unroll
            for (int j = 0; j < 4; ++j) o[j] = f2b(v[j]);
        } else {
            const int rd = row - 1024, kv = rd >> 8, gd = rd & 255;
            const int g = gd >> 6, d = gd & 63;
            const float* W = kv ? Wv : Wk;
            f32x4 sum = {0.f, 0.f, 0.f, 0.f};
            #pragma unroll
            for (int p = 0; p < 4; ++p)
                sum += *(const f32x4*)&W[(size_t)((g*4 + p)*64 + d)*1024 + c];
            #pragma unroll
            for (int j = 0; j < 4; ++j) o[j] = f2b(sum[j]*0.25f);
        }
        *(u16x4*)&wb[idx] = o;
        return;
    }
    q -= NQ_WB;
    if (q < NQ_WO) {
        const int idx = q*4;
        f32x4 v = *(const f32x4*)&Wo[idx];
        u16x4 o;
        #pragma unroll
        for (int j = 0; j < 4; ++j) o[j] = f2b(v[j]);
        *(u16x4*)&wob[idx] = o;
        return;
    }
    q -= NQ_WO;
    if (q < NQ_X) {
        const int idx = q*4;
        f32x4 v = *(const f32x4*)&x[idx];
        u16x4 o;
        #pragma unroll
        for (int j = 0; j < 4; ++j) o[j] = f2b(v[j]);
        *(u16x4*)&xb[idx] = o;
        return;
    }
    q -= NQ_X;
    if (q < (S_*32)/4) {
        const int idx = q*4, s = idx >> 5, f0 = idx & 31;
        #pragma unroll
        for (int j = 0; j < 4; ++j) {
            const float f = (float)(f0 + j);
            const float fr = (float)s * powf(10000.0f, -f*(1.0f/32.0f));
            cost[idx + j] = cosf(fr);
            sint[idx + j] = sinf(fr);
        }
    }
}

// ---------------- MFMA GEMM: C = A(Mx1024) * B(Nx1024)^T, 64x128 tile -------
// MODE 0: fused QKV epilogue (bx<8: Q rope+permute+*C; bx<10: K rope; else V^T)
// MODE 1: fp32 store (O-projection)
template<int MODE>
__global__ __launch_bounds__(256)
void gemm_mfma(const unsigned short* __restrict__ Am,
               const unsigned short* __restrict__ Bm,
               unsigned short* __restrict__ qr,
               unsigned short* __restrict__ kr,
               unsigned short* __restrict__ vt,
               float* __restrict__ outf,
               const float* __restrict__ cost,
               const float* __restrict__ sint,
               int nbx)
{
    __shared__ unsigned short As[2][64*64];    // 16 KB
    __shared__ unsigned short Bs[2][128*64];   // 32 KB

    const int nwg = gridDim.x;
    const int cpx = nwg >> 3;
    const int bid = blockIdx.x;
    const int swz = (bid & 7)*cpx + (bid >> 3);     // XCD-chunked (bijective)
    const int bx = swz % nbx, by = swz / nbx;

    const int t  = threadIdx.x;
    const int w  = t >> 6, l = t & 63;
    const int lg = l >> 4, lr = l & 15;
    const int wr = w >> 1, wc = w & 1;

    const unsigned short* gA = Am + (size_t)by*64*D_;
    const unsigned short* gB = Bm + (size_t)bx*128*D_;

    const int srow = l >> 3;
    const int schk = (l & 7) ^ srow;

#define STAGE(buf, k0)                                                         \
    _Pragma("unroll")                                                          \
    for (int i_ = 0; i_ < 2; ++i_) {                                           \
        const int rowA_ = 16*w + 8*i_ + srow;                                  \
        GLOAD16(gA + (size_t)rowA_*D_ + (k0) + 8*schk, &As[buf][(16*w + 8*i_)*64]); \
    }                                                                          \
    _Pragma("unroll")                                                          \
    for (int i_ = 0; i_ < 4; ++i_) {                                           \
        const int rowB_ = 32*w + 8*i_ + srow;                                  \
        GLOAD16(gB + (size_t)rowB_*D_ + (k0) + 8*schk, &Bs[buf][(32*w + 8*i_)*64]); \
    }

    f32x4 acc[2][4] = {};

    STAGE(0, 0);
    #pragma unroll 1
    for (int kt = 0; kt < 16; ++kt) {
        const int cur = kt & 1;
        if (kt < 15) {
            STAGE(cur ^ 1, 64*(kt + 1));
            asm volatile("s_waitcnt vmcnt(6)" ::: "memory");
        } else {
            asm volatile("s_waitcnt vmcnt(0)" ::: "memory");
        }
        __builtin_amdgcn_s_barrier();

        #pragma unroll
        for (int kk = 0; kk < 2; ++kk) {
            s16x8 af[2], bfr[4];
            #pragma unroll
            for (int m = 0; m < 2; ++m) {
                const int row = 32*wr + 16*m + lr;
                af[m] = *(const s16x8*)&As[cur][row*64 + 8*((lg + 4*kk) ^ (row & 7))];
            }
            #pragma unroll
            for (int n = 0; n < 4; ++n) {
                const int col = 64*wc + 16*n + lr;
                bfr[n] = *(const s16x8*)&Bs[cur][col*64 + 8*((lg + 4*kk) ^ (col & 7))];
            }
            #pragma unroll
            for (int m = 0; m < 2; ++m)
                #pragma unroll
                for (int n = 0; n < 4; ++n)
                    acc[m][n] = MFMA16(af[m], bfr[n], acc[m][n]);
        }
        asm volatile("s_waitcnt lgkmcnt(0)" ::: "memory");
        __builtin_amdgcn_s_barrier();
    }
#undef STAGE

    if (MODE == 1) {
        #pragma unroll
        for (int m = 0; m < 2; ++m)
            #pragma unroll
            for (int r = 0; r < 4; ++r) {
                const int row = by*64 + 32*wr + 16*m + 4*lg + r;
                #pragma unroll
                for (int n = 0; n < 4; ++n)
                    outf[(size_t)row*D_ + bx*128 + 64*wc + 16*n + lr] = acc[m][n][r];
            }
        return;
    }

    if (bx < 10) {   // Q (bx<8) or K (bx 8,9): rope; partner dd^32 = acc[m][n^2]
        const float CQ = 0.18033688011112044f;   // (1/8)*log2(e), folded into Q
        #pragma unroll
        for (int m = 0; m < 2; ++m) {
            #pragma unroll
            for (int r = 0; r < 4; ++r) {
                const int row = by*64 + 32*wr + 16*m + 4*lg + r;
                const int b = row >> 11, s = row & (S_ - 1);
                const float c_lo = cost[s*32 + lr],      s_lo = sint[s*32 + lr];
                const float c_hi = cost[s*32 + 16 + lr], s_hi = sint[s*32 + 16 + lr];
                unsigned short vals[4];
                #pragma unroll
                for (int n = 0; n < 4; ++n) {
                    const float cc = (n & 1) ? c_hi : c_lo;
                    const float sn = (n & 1) ? s_hi : s_lo;
                    const float self = acc[m][n][r], part = acc[m][n ^ 2][r];
                    float rv = (n < 2) ? fmaf(self, cc, -part*sn)
                                       : fmaf(self, cc,  part*sn);
                    if (bx < 8) rv *= CQ;
                    vals[n] = f2b(rv);
                }
                size_t base;
                unsigned short* dst;
                if (bx < 8) {
                    const int hh = 2*bx + wc;
                    const int hp = (hh & 3)*4 + (hh >> 2);  // swapaxes(2,3)
                    base = (((size_t)b*H_ + hp)*S_ + s)*HD_;
                    dst = qr;
                } else {
                    const int g = (bx - 8)*2 + wc;
                    base = (((size_t)b*G_ + g)*S_ + s)*HD_;
                    dst = kr;
                }
                #pragma unroll
                for (int n = 0; n < 4; ++n) dst[base + 16*n + lr] = vals[n];
            }
        }
    } else {         // V: store transposed vt[b][g][dd][s]
        const int g = (bx - 10)*2 + wc;
        #pragma unroll
        for (int m = 0; m < 2; ++m) {
            const int row0 = by*64 + 32*wr + 16*m + 4*lg;
            const int b = row0 >> 11, s0 = row0 & (S_ - 1);
            #pragma unroll
            for (int n = 0; n < 4; ++n) {
                const int dd = 16*n + lr;
                u16x4 v;
                #pragma unroll
                for (int r = 0; r < 4; ++r) v[r] = f2b(acc[m][n][r]);
                *(u16x4*)&vt[(((size_t)b*G_ + g)*HD_ + dd)*S_ + s0] = v;
            }
        }
    }
}

// ---------------- MFMA flash attention: 64 q-rows/wave, in-block split-K2 ---
// 4 waves: (half = w8>>1) keys-half, (wi = w8&1) q-subrange. Each wave owns
// 64 q-rows via TWO Q fragments -> every K/V LDS read feeds 2 MFMAs (halves
// LDS-pipe demand, the measured bottleneck). Max-free softmax (Q pre-scaled
// by (1/8)*log2e), l via ones-MFMA (additive across halves -> LDS combine at
// epilogue, no rescale, no HBM round-trip). One barrier per 64-key iter.
__global__ __launch_bounds__(256, 2)
void flash_attn_mfma(const unsigned short* __restrict__ qr,
                     const unsigned short* __restrict__ kr,
                     const unsigned short* __restrict__ vt,
                     unsigned short* __restrict__ attnb)
{
    __shared__ unsigned short Ks[2][2][64*64];   // [half][dbuf] 8 KB each
    __shared__ unsigned short Vs[2][2][64*64];

    const int bid  = blockIdx.x;
    const int cpx  = gridDim.x >> 3;
    const int swz  = (bid & 7)*cpx + (bid >> 3);   // XCD-chunked
    const int qt   = swz & 15;
    const int h    = (swz >> 4) & 15;
    const int b    = swz >> 8;
    const int g    = h >> 2;
    const int t    = threadIdx.x;
    const int w8   = t >> 6;
    const int half = w8 >> 1;
    const int wi   = w8 & 1;
    const int l    = t & 63;
    const int hi   = l >> 5;
    const int li   = l & 31;

    const unsigned short* Qp = qr + (((size_t)b*H_ + h)*S_ + (size_t)qt*128 + wi*64)*HD_;
    const unsigned short* Kp = kr + ((size_t)b*G_ + g)*(size_t)S_*HD_ + (size_t)half*1024*HD_;
    const unsigned short* Vp = vt + ((size_t)b*G_ + g)*(size_t)HD_*S_ + half*1024;

    s16x8 qf[2][4];            // 2 Q fragments x 4 k-chunks (rows 32f+li)
    #pragma unroll
    for (int f = 0; f < 2; ++f)
        #pragma unroll
        for (int kk = 0; kk < 4; ++kk)
            qf[f][kk] = *(const s16x8*)(Qp + (size_t)(32*f + li)*HD_ + 16*kk + 8*hi);

    s16x8 ones;
    #pragma unroll
    for (int e = 0; e < 8; ++e) ones[e] = (short)0x3F80;   // bf16 1.0

    f32x16 zf;
    #pragma unroll
    for (int e = 0; e < 16; ++e) zf[e] = 0.f;

    f32x16 o[2][2], ol[2];     // [qfrag][dt], [qfrag]
    #pragma unroll
    for (int f = 0; f < 2; ++f) {
        #pragma unroll
        for (int e = 0; e < 16; ++e) { o[f][0][e] = 0.f; o[f][1][e] = 0.f; ol[f][e] = 0.f; }
    }

    const int srow = l >> 3;
    const int schk = (l & 7) ^ srow;

#define STAGE(buf, key0)                                                       \
    _Pragma("unroll")                                                          \
    for (int i_ = 0; i_ < 4; ++i_) {                                           \
        const int row_ = 32*wi + 8*i_ + srow;                                  \
        GLOAD16(Kp + ((size_t)((key0) + row_))*HD_ + 8*schk,                   \
                &Ks[half][buf][(32*wi + 8*i_)*64]);                            \
        GLOAD16(Vp + (size_t)row_*S_ + (key0) + 8*schk,                        \
                &Vs[half][buf][(32*wi + 8*i_)*64]);                            \
    }

    const int NT = 1024/64;    // 16 iters over this half's keys
    STAGE(0, 0);

    #pragma unroll 1
    for (int kt = 0; kt < NT; ++kt) {
        const int cur = kt & 1;
        asm volatile("s_waitcnt vmcnt(0)" ::: "memory");
        __builtin_amdgcn_s_barrier();
        if (kt + 1 < NT) { STAGE(cur ^ 1, 64*(kt + 1)); }

        // ---- QK^T: 8 K-reads feed 16 MFMAs (4 indep chains sc[f][q4]) ----
        f32x16 sc[2][2];
        __builtin_amdgcn_s_setprio(1);
        {
            const int chk = 8*(hi ^ (li & 7));
            s16x8 k0 = *(const s16x8*)&Ks[half][cur][(     li)*64 + chk];
            s16x8 k1 = *(const s16x8*)&Ks[half][cur][(32 + li)*64 + chk];
            sc[0][0] = MFMA32(k0, qf[0][0], zf);
            sc[1][0] = MFMA32(k0, qf[1][0], zf);
            sc[0][1] = MFMA32(k1, qf[0][0], zf);
            sc[1][1] = MFMA32(k1, qf[1][0], zf);
        }
        #pragma unroll
        for (int kk = 1; kk < 4; ++kk) {
            const int chk = 8*((hi + 2*kk) ^ (li & 7));
            s16x8 k0 = *(const s16x8*)&Ks[half][cur][(     li)*64 + chk];
            s16x8 k1 = *(const s16x8*)&Ks[half][cur][(32 + li)*64 + chk];
            sc[0][0] = MFMA32(k0, qf[0][kk], sc[0][0]);
            sc[1][0] = MFMA32(k0, qf[1][kk], sc[1][0]);
            sc[0][1] = MFMA32(k1, qf[0][kk], sc[0][1]);
            sc[1][1] = MFMA32(k1, qf[1][kk], sc[1][1]);
        }
        __builtin_amdgcn_s_setprio(0);

        // ---- P = exp2(sc), 64 batched ----
        #pragma unroll
        for (int f = 0; f < 2; ++f)
            #pragma unroll
            for (int q4 = 0; q4 < 2; ++q4)
                #pragma unroll
                for (int e = 0; e < 16; ++e)
                    sc[f][q4][e] = __builtin_amdgcn_exp2f(sc[f][q4][e]);

        // ---- per-qfrag row-sum slots (for single ones-MFMA each) ----
        float ss0[8], ss1[8];
        #pragma unroll
        for (int j = 0; j < 8; ++j) {
            ss0[j] = (sc[0][0][j] + sc[0][0][8+j]) + (sc[0][1][j] + sc[0][1][8+j]);
            ss1[j] = (sc[1][0][j] + sc[1][0][8+j]) + (sc[1][1][j] + sc[1][1][8+j]);
        }

        // ---- pack + PV: 8 V-reads feed 16 MFMAs (2 qfrags share vf) ----
        __builtin_amdgcn_s_setprio(1);
        #pragma unroll
        for (int q4 = 0; q4 < 2; ++q4) {
            #pragma unroll
            for (int s2 = 0; s2 < 2; ++s2) {
                float t0[8], t1[8];
                #pragma unroll
                for (int j = 0; j < 8; ++j) {
                    t0[j] = sc[0][q4][8*s2 + j];
                    t1[j] = sc[1][q4][8*s2 + j];
                }
                s16x8 pa0 = pack8(t0);
                s16x8 pa1 = pack8(t1);
                const int ks_ = 2*q4 + s2;
                #pragma unroll
                for (int dt = 0; dt < 2; ++dt) {
                    const int d = li + 32*dt;
                    s16x8 vf = *(const s16x8*)&Vs[half][cur][d*64 + 8*((hi + 2*ks_) ^ (li & 7))];
                    o[0][dt] = MFMA32(pa0, vf, o[0][dt]);
                    o[1][dt] = MFMA32(pa1, vf, o[1][dt]);
                }
            }
        }
        {
            s16x8 ps0 = pack8(ss0);
            s16x8 ps1 = pack8(ss1);
            ol[0] = MFMA32(ps0, ones, ol[0]);
            ol[1] = MFMA32(ps1, ones, ol[1]);
        }
        __builtin_amdgcn_s_setprio(0);
    }
#undef STAGE

    // ---- epilogue: combine key-halves through LDS (pure adds, max-free) ----
    float* ocomb = (float*)&Ks[0][0][0];    // 128 q x 64 d f32 = 32 KB
    float* lcomb = (float*)&Vs[0][0][0];    // 128 f32
    __syncthreads();

    if (half == 1) {
        #pragma unroll
        for (int f = 0; f < 2; ++f)
            #pragma unroll
            for (int r = 0; r < 16; ++r) {
                const int qq  = (r & 3) + 8*(r >> 2) + 4*hi;
                const int row = 64*wi + 32*f + qq;
                ocomb[row*64 + li]      = o[f][0][r];
                ocomb[row*64 + li + 32] = o[f][1][r];
                if (li == 0) lcomb[row] = ol[f][r];
            }
    }
    __syncthreads();
    if (half == 0) {
        #pragma unroll
        for (int f = 0; f < 2; ++f)
            #pragma unroll
            for (int r = 0; r < 16; ++r) {
                const int qq  = (r & 3) + 8*(r >> 2) + 4*hi;
                const int row = 64*wi + 32*f + qq;
                const int s   = qt*128 + row;
                const float inv = 1.0f / (ol[f][r] + lcomb[row]);
                #pragma unroll
                for (int dt = 0; dt < 2; ++dt) {
                    const float v = (o[f][dt][r] + ocomb[row*64 + li + 32*dt]) * inv;
                    attnb[((size_t)b*S_ + s)*D_ + h*HD_ + li + 32*dt] = f2b(v);
                }
            }
    }
}

extern "C" void kernel_launch(void* const* d_in, const int* in_sizes, int n_in,
                              void* d_out, int out_size, void* d_ws, size_t ws_size,
                              hipStream_t stream)
{
    const float* x  = (const float*)d_in[0];
    const float* Wq = (const float*)d_in[1];
    const float* Wk = (const float*)d_in[2];
    const float* Wv = (const float*)d_in[3];
    const float* Wo = (const float*)d_in[4];
    float* out = (float*)d_out;

    char* p = (char*)d_ws;
    unsigned short* xb    = (unsigned short*)p; p += (size_t)B_*S_*D_*2;      // 8 MB
    unsigned short* wb    = (unsigned short*)p; p += (size_t)1536*1024*2;     // 3 MB
    unsigned short* wob   = (unsigned short*)p; p += (size_t)1024*1024*2;     // 2 MB
    unsigned short* qr    = (unsigned short*)p; p += (size_t)B_*H_*S_*HD_*2;  // 8 MB
    unsigned short* kr    = (unsigned short*)p; p += (size_t)B_*G_*S_*HD_*2;  // 2 MB
    unsigned short* vt    = (unsigned short*)p; p += (size_t)B_*G_*HD_*S_*2;  // 2 MB
    unsigned short* attnb = (unsigned short*)p; p += (size_t)B_*S_*D_*2;      // 8 MB
    float* cost = (float*)p; p += (size_t)S_*32*4;
    float* sint = (float*)p;

    prep_all<<<6720, 256, 0, stream>>>(x, Wq, Wk, Wv, Wo, xb, wb, wob, cost, sint);
    gemm_mfma<0><<<64*12, 256, 0, stream>>>(xb, wb, qr, kr, vt, nullptr, cost, sint, 12);
    flash_attn_mfma<<<B_*H_*(S_/128), 256, 0, stream>>>(qr, kr, vt, attnb);
    gemm_mfma<1><<<64*8, 256, 0, stream>>>(attnb, wob, nullptr, nullptr, nullptr, out, cost, sint, 8);
}